// Round 19
// baseline (178.537 us; speedup 1.0000x reference)
//
#include <hip/hip_runtime.h>

#define Bsz 64
#define Lsz 4096
#define Dsz 512
#define Hsz 512
#define Usz 256
#define LT  32
#define NLB (Lsz / LT)          // 128 L-tiles per batch -> 8192 blocks

typedef __attribute__((ext_vector_type(8))) short s8v;     // bf16x8 MFMA frag
typedef __attribute__((ext_vector_type(4))) float f4v;
typedef __attribute__((ext_vector_type(8))) unsigned short u16x8;

// XOR swizzle: 16B slot (8 shorts) ^= row&7 (bijective, b128-aligned)
#define SW(r, c) (((((c) >> 3) ^ ((r) & 7)) << 3) | ((c) & 7))

__device__ __forceinline__ unsigned short f2bf(float f) {
    unsigned int u = __float_as_uint(f);
    u += 0x7FFFu + ((u >> 16) & 1u);   // RNE
    return (unsigned short)(u >> 16);
}
__device__ __forceinline__ float bf2f(unsigned int lo16) {
    return __uint_as_float(lo16 << 16);
}
__device__ __forceinline__ void barrier_lds() {
    asm volatile("s_waitcnt lgkmcnt(0)" ::: "memory");
    __builtin_amdgcn_s_barrier();
}

// ws layout
//   [0,     256K)      : W1Tf bf16, FRAGMENT-ORDER: [kb32][colgrp][lg][lr][8]
//   [256K,  512K)      : hp_part f32 [4][64][256]
//   [512K, 1536K)      : el_arr f32 [64][4096]
//   [1536K, +256B)     : den f32 [64]
//   [1536K+256, +128K) : ctx_acc f32 [64][512]

__global__ __launch_bounds__(256) void k_prep(const float* __restrict__ W1,
                                              const float* __restrict__ hidden,
                                              const float* __restrict__ W2,
                                              unsigned short* __restrict__ W1Tf,
                                              float* __restrict__ hp_part,
                                              float* __restrict__ den,
                                              float* __restrict__ ctx_acc) {
    int blk = blockIdx.x, tid = threadIdx.x;
    if (blk < 32) {
        __shared__ unsigned short Lt[64][72];   // [k within 64][u within 64], padded
        int kb = blk >> 2, ub = blk & 3;        // 64-k block, 64-u block
        {
            int rr = tid >> 2, c16 = (tid & 3) * 16;   // k-row, u-chunk
            const float* src = W1 + (size_t)(kb * 64 + rr) * Usz + ub * 64 + c16;
            f4v v0 = *reinterpret_cast<const f4v*>(src);
            f4v v1 = *reinterpret_cast<const f4v*>(src + 4);
            f4v v2 = *reinterpret_cast<const f4v*>(src + 8);
            f4v v3 = *reinterpret_cast<const f4v*>(src + 12);
            u16x8 o0 = { f2bf(v0.x), f2bf(v0.y), f2bf(v0.z), f2bf(v0.w),
                         f2bf(v1.x), f2bf(v1.y), f2bf(v1.z), f2bf(v1.w) };
            u16x8 o1 = { f2bf(v2.x), f2bf(v2.y), f2bf(v2.z), f2bf(v2.w),
                         f2bf(v3.x), f2bf(v3.y), f2bf(v3.z), f2bf(v3.w) };
            *reinterpret_cast<u16x8*>(&Lt[rr][c16])     = o0;
            *reinterpret_cast<u16x8*>(&Lt[rr][c16 + 8]) = o1;
        }
        __syncthreads();
        {
            int ur = tid >> 2, k16 = (tid & 3) * 16;   // u-row, k-chunk (16 k's)
            u16x8 o0, o1;
#pragma unroll
            for (int i = 0; i < 8; ++i) o0[i] = Lt[k16 + i][ur];
#pragma unroll
            for (int i = 0; i < 8; ++i) o1[i] = Lt[k16 + 8 + i][ur];
            const int kb32 = kb * 2 + (k16 >> 5);
            const int lg0  = (k16 >> 3) & 3;
            const int cg   = ub * 4 + (ur >> 4);
            const int lr   = ur & 15;
            unsigned short* d0 = W1Tf + ((size_t)(kb32 * 16 + cg) * 512) + (lg0 * 16 + lr) * 8;
            unsigned short* d1 = W1Tf + ((size_t)(kb32 * 16 + cg) * 512) + ((lg0 + 1) * 16 + lr) * 8;
            *reinterpret_cast<u16x8*>(d0) = o0;
            *reinterpret_cast<u16x8*>(d1) = o1;
        }
    } else if (blk < 288) {
        int idx = blk - 32;
        int kq = idx >> 6, b = idx & 63;
        const float* hrow = hidden + (size_t)b * Hsz + kq * 128;
        const float* w2p  = W2 + (size_t)(kq * 128) * Usz + tid;
        float a0 = 0.f, a1 = 0.f, a2 = 0.f, a3 = 0.f;
#pragma unroll 8
        for (int k = 0; k < 128; k += 4) {
            a0 = fmaf(hrow[k + 0], w2p[(size_t)(k + 0) * Usz], a0);
            a1 = fmaf(hrow[k + 1], w2p[(size_t)(k + 1) * Usz], a1);
            a2 = fmaf(hrow[k + 2], w2p[(size_t)(k + 2) * Usz], a2);
            a3 = fmaf(hrow[k + 3], w2p[(size_t)(k + 3) * Usz], a3);
        }
        hp_part[((size_t)kq * Bsz + b) * Usz + tid] = (a0 + a1) + (a2 + a3);
    } else {
        int b = blk - 288;
        if (tid == 0) den[b] = 0.f;
        ctx_acc[b * Dsz + tid] = 0.f;
        ctx_acc[b * Dsz + 256 + tid] = 0.f;
    }
}

// LT=32, 8192 blocks x 512 thr (8 waves x 32 U-cols). LDS ~39KB -> 4 blocks/CU
// (8 waves/SIMD) for statistical phase interleave. Fragment-order B loads
// (contiguous 1KB wave-loads, R18's win). B prefetch in k-pair groups
// (bq[2][2]=16 regs) to fit the 64-VGPR/wave budget at 8 waves/EU.
__global__ void __launch_bounds__(512)
__attribute__((amdgpu_waves_per_eu(8, 8))) k_score_ctx(
    const float* __restrict__ feat, const unsigned short* __restrict__ W1Tf,
    const float* __restrict__ hp_part, const float* __restrict__ W1b,
    const float* __restrict__ W2b, const float* __restrict__ Vk,
    const float* __restrict__ Vb, float* __restrict__ el_arr,
    float* __restrict__ den, float* __restrict__ ctx_acc)
{
    __shared__ __align__(16) unsigned short A[LT][Dsz];  // 32 KiB, swizzled
    __shared__ float hp[Usz], vv[Usz];
    __shared__ float spart[8][LT];
    __shared__ float el[LT];
    __shared__ float pc[2][Dsz];

    const int tid  = threadIdx.x;
    const int w    = tid >> 6;
    const int lane = tid & 63;
    const int lr   = lane & 15;
    const int lg   = lane >> 4;
    const int b    = blockIdx.x >> 7;
    const int lb   = blockIdx.x & 127;
    const int l0   = lb * LT;

    const int srow = tid >> 4;            // 0..31
    const int sfc  = (tid & 15) * 8;      // float col within 128-chunk
    const float* fb = feat + ((size_t)b * Lsz + l0 + srow) * Dsz + sfc;

    // ---- prologue: issue chunk0+1 loads (2 f4v each) ----
    f4v st[2][2];
    st[0][0] = *reinterpret_cast<const f4v*>(fb);
    st[0][1] = *reinterpret_cast<const f4v*>(fb + 4);
    st[1][0] = *reinterpret_cast<const f4v*>(fb + 128);
    st[1][1] = *reinterpret_cast<const f4v*>(fb + 132);
    __builtin_amdgcn_sched_barrier(0);

    if (tid < Usz) {
        const float* hpb = hp_part + (size_t)b * Usz + tid;
        hp[tid] = (hpb[0] + hpb[Bsz * Usz]) + (hpb[2 * Bsz * Usz] + hpb[3 * Bsz * Usz])
                + W1b[tid] + W2b[tid];
        vv[tid] = Vk[tid];
    }

#pragma unroll
    for (int c = 0; c < 4; ++c) {
        // write chunk c (waits only its own loads; later loads stay in flight)
        {
            const f4v* s = st[c & 1];
            const int cc = c * 128 + sfc;
            u16x8 o = { f2bf(s[0].x), f2bf(s[0].y), f2bf(s[0].z), f2bf(s[0].w),
                        f2bf(s[1].x), f2bf(s[1].y), f2bf(s[1].z), f2bf(s[1].w) };
            *reinterpret_cast<u16x8*>(&A[srow][SW(srow, cc)]) = o;
        }
        if (c < 2) {
            st[c & 1][0] = *reinterpret_cast<const f4v*>(fb + (c + 2) * 128);
            st[c & 1][1] = *reinterpret_cast<const f4v*>(fb + (c + 2) * 128 + 4);
        }
        __builtin_amdgcn_sched_barrier(0);
    }
    barrier_lds();

    // ---- GEMM: 32 rows x this wave's 32 cols x K=512, fragment-order B ----
    const unsigned short* bpf = W1Tf + (size_t)(w * 2) * 512 + lane * 8;
    f4v acc[2][2];
    acc[0][0] = (f4v){0.f, 0.f, 0.f, 0.f};
    acc[0][1] = (f4v){0.f, 0.f, 0.f, 0.f};
    acc[1][0] = (f4v){0.f, 0.f, 0.f, 0.f};
    acc[1][1] = (f4v){0.f, 0.f, 0.f, 0.f};

#pragma unroll
    for (int c = 0; c < 4; ++c) {
#pragma unroll
        for (int g = 0; g < 2; ++g) {
            s8v bq[2][2];
#pragma unroll
            for (int k = 0; k < 2; ++k) {
                const size_t kbo = (size_t)((c * 4 + g * 2 + k) * 16) * 512;
                bq[k][0] = *reinterpret_cast<const s8v*>(bpf + kbo);
                bq[k][1] = *reinterpret_cast<const s8v*>(bpf + kbo + 512);
            }
            __builtin_amdgcn_sched_barrier(0);
#pragma unroll
            for (int k = 0; k < 2; ++k) {
                const int kof = (c * 4 + g * 2 + k) * 32 + lg * 8;
#pragma unroll
                for (int mf = 0; mf < 2; ++mf) {
                    const int row = mf * 16 + lr;
                    s8v a = *reinterpret_cast<const s8v*>(&A[row][SW(row, kof)]);
                    acc[mf][0] = __builtin_amdgcn_mfma_f32_16x16x32_bf16(a, bq[k][0], acc[mf][0], 0, 0, 0);
                    acc[mf][1] = __builtin_amdgcn_mfma_f32_16x16x32_bf16(a, bq[k][1], acc[mf][1], 0, 0, 0);
                }
            }
        }
    }

    // ---- epilogue: per-row sum of tanh(x)*V over this wave's 32 cols ----
    {
        float rs[2][4];
#pragma unroll
        for (int mf = 0; mf < 2; ++mf)
#pragma unroll
            for (int r = 0; r < 4; ++r) rs[mf][r] = 0.f;
#pragma unroll
        for (int mf = 0; mf < 2; ++mf)
#pragma unroll
            for (int nf = 0; nf < 2; ++nf) {
                int col = w * 32 + nf * 16 + lr;
                float hpv = hp[col], vvv = vv[col];
#pragma unroll
                for (int r = 0; r < 4; ++r) {
                    float x = acc[mf][nf][r] + hpv;
                    float e = __expf(2.f * x);
                    rs[mf][r] = fmaf(1.f - 2.f / (e + 1.f), vvv, rs[mf][r]);
                }
            }
#pragma unroll
        for (int off = 1; off < 16; off <<= 1)
#pragma unroll
            for (int mf = 0; mf < 2; ++mf)
#pragma unroll
                for (int r = 0; r < 4; ++r)
                    rs[mf][r] += __shfl_xor(rs[mf][r], off, 64);
        if (lr == 0)
#pragma unroll
            for (int mf = 0; mf < 2; ++mf)
#pragma unroll
                for (int r = 0; r < 4; ++r)
                    spart[w][mf * 16 + lg * 4 + r] = rs[mf][r];
    }
    barrier_lds();

    // ---- scores -> exp -> denominator (lanes 0..31 of wave 0) ----
    if (tid < LT) {
        float s = Vb[0];
#pragma unroll
        for (int ww = 0; ww < 8; ++ww) s += spart[ww][tid];
        float e = __expf(s);
        el[tid] = e;
        el_arr[(size_t)b * Lsz + l0 + tid] = e;
        float es = e;
#pragma unroll
        for (int off = 1; off < 32; off <<= 1) es += __shfl_xor(es, off, 64);
        if (tid == 0) atomicAdd(&den[b], es);
    }
    barrier_lds();

    // ---- context: u32 swizzled reads, two 16-row halves, pc-reduce ----
    {
        const int qr = tid >> 8;            // 0..1
        const int d0 = (tid & 255) * 2;
        float a0 = 0.f, a1 = 0.f;
#pragma unroll
        for (int li = 0; li < 16; ++li) {
            int l = qr * 16 + li;
            unsigned int pk = *reinterpret_cast<const unsigned int*>(&A[l][SW(l, d0)]);
            float e = el[l];
            a0 = fmaf(e, bf2f(pk & 0xFFFFu), a0);
            a1 = fmaf(e, bf2f(pk >> 16), a1);
        }
        pc[qr][d0]     = a0;
        pc[qr][d0 + 1] = a1;
    }
    barrier_lds();
    atomicAdd(&ctx_acc[b * Dsz + tid], pc[0][tid] + pc[1][tid]);
}

__global__ __launch_bounds__(256) void k_finalize(const float* __restrict__ el_arr,
                                                  const float* __restrict__ den,
                                                  const float* __restrict__ ctx_acc,
                                                  float* __restrict__ ctx,
                                                  float* __restrict__ wout) {
    int blk = blockIdx.x, tid = threadIdx.x;
    int b = blk >> 2, q = blk & 3;
    float inv = 1.f / den[b];
    size_t base = (size_t)b * Lsz + q * 1024 + tid * 4;
    f4v e4 = *reinterpret_cast<const f4v*>(&el_arr[base]);
    f4v w4 = { e4.x * inv, e4.y * inv, e4.z * inv, e4.w * inv };
    *reinterpret_cast<f4v*>(&wout[base]) = w4;
    if (tid < 128) {
        int d = q * 128 + tid;
        ctx[(size_t)b * Dsz + d] = ctx_acc[b * Dsz + d] * inv;
    }
}

extern "C" void kernel_launch(void* const* d_in, const int* in_sizes, int n_in,
                              void* d_out, int out_size, void* d_ws, size_t ws_size,
                              hipStream_t stream) {
    const float* feat   = (const float*)d_in[0];
    const float* hidden = (const float*)d_in[1];
    const float* W1     = (const float*)d_in[2];
    const float* W1b    = (const float*)d_in[3];
    const float* W2     = (const float*)d_in[4];
    const float* W2b    = (const float*)d_in[5];
    const float* Vk     = (const float*)d_in[6];
    const float* Vb     = (const float*)d_in[7];

    unsigned short* w1tf = (unsigned short*)d_ws;
    float* hp_part = (float*)((char*)d_ws + 256 * 1024);
    float* el_arr  = (float*)((char*)d_ws + 512 * 1024);
    float* den     = (float*)((char*)d_ws + 1536 * 1024);
    float* ctx_acc = (float*)((char*)d_ws + 1536 * 1024 + 256);

    float* ctx  = (float*)d_out;              // [64, 512]
    float* wout = ctx + Bsz * Dsz;            // [64, 4096, 1]

    k_prep<<<352, 256, 0, stream>>>(W1, hidden, W2, w1tf, hp_part, den, ctx_acc);
    k_score_ctx<<<Bsz * NLB, 512, 0, stream>>>(feat, w1tf, hp_part, W1b, W2b,
                                               Vk, Vb, el_arr, den, ctx_acc);
    k_finalize<<<Bsz * 4, 256, 0, stream>>>(el_arr, den, ctx_acc, ctx, wout);
}

// Round 20
// 164.038 us; speedup vs baseline: 1.0884x; 1.0884x over previous
//
#include <hip/hip_runtime.h>

#define Bsz 64
#define Lsz 4096
#define Dsz 512
#define Hsz 512
#define Usz 256
#define LT  64
#define NLB (Lsz / LT)          // 64 L-tiles per batch -> 4096 blocks

typedef __attribute__((ext_vector_type(8))) short s8v;     // bf16x8 MFMA frag
typedef __attribute__((ext_vector_type(4))) float f4v;
typedef __attribute__((ext_vector_type(8))) unsigned short u16x8;

// XOR swizzle on a [64][512]-short row: 16B slot ^= row&7 (bijective, b128-aligned)
#define SW(r, c) (((((c) >> 3) ^ ((r) & 7)) << 3) | ((c) & 7))

__device__ __forceinline__ unsigned short f2bf(float f) {
    unsigned int u = __float_as_uint(f);
    u += 0x7FFFu + ((u >> 16) & 1u);   // RNE
    return (unsigned short)(u >> 16);
}
__device__ __forceinline__ float bf2f(unsigned int lo16) {
    return __uint_as_float(lo16 << 16);
}
__device__ __forceinline__ void barrier_lds() {
    asm volatile("s_waitcnt lgkmcnt(0)" ::: "memory");
    __builtin_amdgcn_s_barrier();
}

// ws layout
//   [0,     256K)      : W1Tf bf16, FRAGMENT-ORDER: [kb32][colgrp][lg][lr][8]
//                        element (k,u) at ((k>>5)*16 + (u>>4))*512 + (((k>>3)&3)*16 + (u&15))*8 + (k&7)
//   [256K,  512K)      : hp_part f32 [4][64][256]
//   [512K, 1536K)      : el_arr f32 [64][4096]
//   [1536K, +256B)     : den f32 [64]
//   [1536K+256, +128K) : ctx_acc f32 [64][512]

__global__ __launch_bounds__(256) void k_prep(const float* __restrict__ W1,
                                              const float* __restrict__ hidden,
                                              const float* __restrict__ W2,
                                              unsigned short* __restrict__ W1Tf,
                                              float* __restrict__ hp_part,
                                              float* __restrict__ den,
                                              float* __restrict__ ctx_acc) {
    int blk = blockIdx.x, tid = threadIdx.x;
    if (blk < 32) {
        __shared__ unsigned short Lt[64][72];   // [k within 64][u within 64], padded
        int kb = blk >> 2, ub = blk & 3;        // 64-k block, 64-u block
        {
            int rr = tid >> 2, c16 = (tid & 3) * 16;   // k-row, u-chunk
            const float* src = W1 + (size_t)(kb * 64 + rr) * Usz + ub * 64 + c16;
            f4v v0 = *reinterpret_cast<const f4v*>(src);
            f4v v1 = *reinterpret_cast<const f4v*>(src + 4);
            f4v v2 = *reinterpret_cast<const f4v*>(src + 8);
            f4v v3 = *reinterpret_cast<const f4v*>(src + 12);
            u16x8 o0 = { f2bf(v0.x), f2bf(v0.y), f2bf(v0.z), f2bf(v0.w),
                         f2bf(v1.x), f2bf(v1.y), f2bf(v1.z), f2bf(v1.w) };
            u16x8 o1 = { f2bf(v2.x), f2bf(v2.y), f2bf(v2.z), f2bf(v2.w),
                         f2bf(v3.x), f2bf(v3.y), f2bf(v3.z), f2bf(v3.w) };
            *reinterpret_cast<u16x8*>(&Lt[rr][c16])     = o0;
            *reinterpret_cast<u16x8*>(&Lt[rr][c16 + 8]) = o1;
        }
        __syncthreads();
        {
            int ur = tid >> 2, k16 = (tid & 3) * 16;   // u-row, k-chunk (16 k's)
            u16x8 o0, o1;
#pragma unroll
            for (int i = 0; i < 8; ++i) o0[i] = Lt[k16 + i][ur];       // k = kb*64+k16+i
#pragma unroll
            for (int i = 0; i < 8; ++i) o1[i] = Lt[k16 + 8 + i][ur];   // k = kb*64+k16+8+i
            // fragment-order destination
            const int kb32 = kb * 2 + (k16 >> 5);          // 32-k block
            const int lg0  = (k16 >> 3) & 3;               // 0 or 2
            const int cg   = ub * 4 + (ur >> 4);           // 16-col group
            const int lr   = ur & 15;
            unsigned short* d0 = W1Tf + ((size_t)(kb32 * 16 + cg) * 512) + (lg0 * 16 + lr) * 8;
            unsigned short* d1 = W1Tf + ((size_t)(kb32 * 16 + cg) * 512) + ((lg0 + 1) * 16 + lr) * 8;
            *reinterpret_cast<u16x8*>(d0) = o0;
            *reinterpret_cast<u16x8*>(d1) = o1;
        }
    } else if (blk < 288) {
        int idx = blk - 32;
        int kq = idx >> 6, b = idx & 63;
        const float* hrow = hidden + (size_t)b * Hsz + kq * 128;
        const float* w2p  = W2 + (size_t)(kq * 128) * Usz + tid;
        float a0 = 0.f, a1 = 0.f, a2 = 0.f, a3 = 0.f;
#pragma unroll 8
        for (int k = 0; k < 128; k += 4) {
            a0 = fmaf(hrow[k + 0], w2p[(size_t)(k + 0) * Usz], a0);
            a1 = fmaf(hrow[k + 1], w2p[(size_t)(k + 1) * Usz], a1);
            a2 = fmaf(hrow[k + 2], w2p[(size_t)(k + 2) * Usz], a2);
            a3 = fmaf(hrow[k + 3], w2p[(size_t)(k + 3) * Usz], a3);
        }
        hp_part[((size_t)kq * Bsz + b) * Usz + tid] = (a0 + a1) + (a2 + a3);
    } else {
        int b = blk - 288;
        if (tid == 0) den[b] = 0.f;
        ctx_acc[b * Dsz + tid] = 0.f;
        ctx_acc[b * Dsz + 256 + tid] = 0.f;
    }
}

// R11 pipeline (best measured) with FRAGMENT-ORDER B loads:
// every B-frag load is base + lane*16B -> one contiguous 1KB wave-load
// (16 consecutive 64B segments) instead of 16 segments at 1KB stride.
__global__ void __launch_bounds__(512)
__attribute__((amdgpu_waves_per_eu(4, 4))) k_score_ctx(
    const float* __restrict__ feat, const unsigned short* __restrict__ W1Tf,
    const float* __restrict__ hp_part, const float* __restrict__ W1b,
    const float* __restrict__ W2b, const float* __restrict__ Vk,
    const float* __restrict__ Vb, float* __restrict__ el_arr,
    float* __restrict__ den, float* __restrict__ ctx_acc)
{
    __shared__ __align__(16) unsigned short A[LT][Dsz];  // 64 KiB, swizzled
    __shared__ float hp[Usz], vv[Usz];
    __shared__ float spart[8][LT];
    __shared__ float el[LT];
    __shared__ float pc[2][Dsz];

    const int tid  = threadIdx.x;
    const int w    = tid >> 6;
    const int lane = tid & 63;
    const int lr   = lane & 15;
    const int lg   = lane >> 4;
    const int b    = blockIdx.x >> 6;
    const int lb   = blockIdx.x & 63;
    const int l0   = lb * LT;

    const int srow = tid >> 3;
    const int sfc  = (tid & 7) * 16;
    const float* fb = feat + ((size_t)b * Lsz + l0 + srow) * Dsz + sfc;

    f4v st[2][4];
#pragma unroll
    for (int i = 0; i < 4; ++i) st[0][i] = *reinterpret_cast<const f4v*>(fb + i * 4);
#pragma unroll
    for (int i = 0; i < 4; ++i) st[1][i] = *reinterpret_cast<const f4v*>(fb + 128 + i * 4);
    __builtin_amdgcn_sched_barrier(0);

    if (tid < Usz) {
        const float* hpb = hp_part + (size_t)b * Usz + tid;
        hp[tid] = (hpb[0] + hpb[Bsz * Usz]) + (hpb[2 * Bsz * Usz] + hpb[3 * Bsz * Usz])
                + W1b[tid] + W2b[tid];
        vv[tid] = Vk[tid];
    }
    {
        u16x8 o0 = { f2bf(st[0][0].x), f2bf(st[0][0].y), f2bf(st[0][0].z), f2bf(st[0][0].w),
                     f2bf(st[0][1].x), f2bf(st[0][1].y), f2bf(st[0][1].z), f2bf(st[0][1].w) };
        u16x8 o1 = { f2bf(st[0][2].x), f2bf(st[0][2].y), f2bf(st[0][2].z), f2bf(st[0][2].w),
                     f2bf(st[0][3].x), f2bf(st[0][3].y), f2bf(st[0][3].z), f2bf(st[0][3].w) };
        *reinterpret_cast<u16x8*>(&A[srow][SW(srow, sfc)])     = o0;
        *reinterpret_cast<u16x8*>(&A[srow][SW(srow, sfc + 8)]) = o1;
    }
    barrier_lds();

    // fragment-order B base: frag (kb, cg=w*2+nf) at (kb*16+cg)*512 shorts, + lane*8
    const unsigned short* bpf = W1Tf + (size_t)(w * 2) * 512 + lane * 8;
    f4v acc[4][2];
#pragma unroll
    for (int mf = 0; mf < 4; ++mf) {
        acc[mf][0] = (f4v){0.f, 0.f, 0.f, 0.f};
        acc[mf][1] = (f4v){0.f, 0.f, 0.f, 0.f};
    }

#pragma unroll
    for (int c = 0; c < 4; ++c) {
        s8v bq[4][2];
#pragma unroll
        for (int k = 0; k < 4; ++k) {
            const size_t kbo = (size_t)((c * 4 + k) * 16) * 512;
            bq[k][0] = *reinterpret_cast<const s8v*>(bpf + kbo);
            bq[k][1] = *reinterpret_cast<const s8v*>(bpf + kbo + 512);
        }
        __builtin_amdgcn_sched_barrier(0);
        if (c < 2) {
#pragma unroll
            for (int i = 0; i < 4; ++i)
                st[c & 1][i] = *reinterpret_cast<const f4v*>(fb + (c + 2) * 128 + i * 4);
        }
        __builtin_amdgcn_sched_barrier(0);
#pragma unroll
        for (int k = 0; k < 4; ++k) {
            const int kof = (c * 4 + k) * 32 + lg * 8;
#pragma unroll
            for (int mf = 0; mf < 4; ++mf) {
                const int row = mf * 16 + lr;
                s8v a = *reinterpret_cast<const s8v*>(&A[row][SW(row, kof)]);
                acc[mf][0] = __builtin_amdgcn_mfma_f32_16x16x32_bf16(a, bq[k][0], acc[mf][0], 0, 0, 0);
                acc[mf][1] = __builtin_amdgcn_mfma_f32_16x16x32_bf16(a, bq[k][1], acc[mf][1], 0, 0, 0);
            }
        }
        __builtin_amdgcn_sched_barrier(0);
        if (c < 3) {
            const int cc = (c + 1) * 128 + sfc;
            const f4v* s = st[(c + 1) & 1];
            u16x8 o0 = { f2bf(s[0].x), f2bf(s[0].y), f2bf(s[0].z), f2bf(s[0].w),
                         f2bf(s[1].x), f2bf(s[1].y), f2bf(s[1].z), f2bf(s[1].w) };
            u16x8 o1 = { f2bf(s[2].x), f2bf(s[2].y), f2bf(s[2].z), f2bf(s[2].w),
                         f2bf(s[3].x), f2bf(s[3].y), f2bf(s[3].z), f2bf(s[3].w) };
            *reinterpret_cast<u16x8*>(&A[srow][SW(srow, cc)])     = o0;
            *reinterpret_cast<u16x8*>(&A[srow][SW(srow, cc + 8)]) = o1;
            barrier_lds();
        }
    }

    {
        float rs[4][4];
#pragma unroll
        for (int mf = 0; mf < 4; ++mf)
#pragma unroll
            for (int r = 0; r < 4; ++r) rs[mf][r] = 0.f;
#pragma unroll
        for (int mf = 0; mf < 4; ++mf)
#pragma unroll
            for (int nf = 0; nf < 2; ++nf) {
                int col = w * 32 + nf * 16 + lr;
                float hpv = hp[col], vvv = vv[col];
#pragma unroll
                for (int r = 0; r < 4; ++r) {
                    float x = acc[mf][nf][r] + hpv;
                    float e = __expf(2.f * x);
                    rs[mf][r] = fmaf(1.f - 2.f / (e + 1.f), vvv, rs[mf][r]);
                }
            }
#pragma unroll
        for (int off = 1; off < 16; off <<= 1)
#pragma unroll
            for (int mf = 0; mf < 4; ++mf)
#pragma unroll
                for (int r = 0; r < 4; ++r)
                    rs[mf][r] += __shfl_xor(rs[mf][r], off, 64);
        if (lr == 0)
#pragma unroll
            for (int mf = 0; mf < 4; ++mf)
#pragma unroll
                for (int r = 0; r < 4; ++r)
                    spart[w][mf * 16 + lg * 4 + r] = rs[mf][r];
    }
    barrier_lds();

    if (tid < LT) {
        float s = Vb[0];
#pragma unroll
        for (int ww = 0; ww < 8; ++ww) s += spart[ww][tid];
        float e = __expf(s);
        el[tid] = e;
        el_arr[(size_t)b * Lsz + l0 + tid] = e;
        float es = e;
#pragma unroll
        for (int off = 1; off < 64; off <<= 1) es += __shfl_xor(es, off, 64);
        if (tid == 0) atomicAdd(&den[b], es);
    }
    barrier_lds();

    {
        const int qr = tid >> 8;
        const int d0 = (tid & 255) * 2;
        float a0 = 0.f, a1 = 0.f;
#pragma unroll 8
        for (int li = 0; li < 32; ++li) {
            int l = qr * 32 + li;
            unsigned int pk = *reinterpret_cast<const unsigned int*>(&A[l][SW(l, d0)]);
            float e = el[l];
            a0 = fmaf(e, bf2f(pk & 0xFFFFu), a0);
            a1 = fmaf(e, bf2f(pk >> 16), a1);
        }
        pc[qr][d0]     = a0;
        pc[qr][d0 + 1] = a1;
    }
    barrier_lds();
    atomicAdd(&ctx_acc[b * Dsz + tid], pc[0][tid] + pc[1][tid]);
}

__global__ __launch_bounds__(256) void k_finalize(const float* __restrict__ el_arr,
                                                  const float* __restrict__ den,
                                                  const float* __restrict__ ctx_acc,
                                                  float* __restrict__ ctx,
                                                  float* __restrict__ wout) {
    int blk = blockIdx.x, tid = threadIdx.x;
    int b = blk >> 2, q = blk & 3;
    float inv = 1.f / den[b];
    size_t base = (size_t)b * Lsz + q * 1024 + tid * 4;
    f4v e4 = *reinterpret_cast<const f4v*>(&el_arr[base]);
    f4v w4 = { e4.x * inv, e4.y * inv, e4.z * inv, e4.w * inv };
    *reinterpret_cast<f4v*>(&wout[base]) = w4;
    if (tid < 128) {
        int d = q * 128 + tid;
        ctx[(size_t)b * Dsz + d] = ctx_acc[b * Dsz + d] * inv;
    }
}

extern "C" void kernel_launch(void* const* d_in, const int* in_sizes, int n_in,
                              void* d_out, int out_size, void* d_ws, size_t ws_size,
                              hipStream_t stream) {
    const float* feat   = (const float*)d_in[0];
    const float* hidden = (const float*)d_in[1];
    const float* W1     = (const float*)d_in[2];
    const float* W1b    = (const float*)d_in[3];
    const float* W2     = (const float*)d_in[4];
    const float* W2b    = (const float*)d_in[5];
    const float* Vk     = (const float*)d_in[6];
    const float* Vb     = (const float*)d_in[7];

    unsigned short* w1tf = (unsigned short*)d_ws;
    float* hp_part = (float*)((char*)d_ws + 256 * 1024);
    float* el_arr  = (float*)((char*)d_ws + 512 * 1024);
    float* den     = (float*)((char*)d_ws + 1536 * 1024);
    float* ctx_acc = (float*)((char*)d_ws + 1536 * 1024 + 256);

    float* ctx  = (float*)d_out;              // [64, 512]
    float* wout = ctx + Bsz * Dsz;            // [64, 4096, 1]

    k_prep<<<352, 256, 0, stream>>>(W1, hidden, W2, w1tf, hp_part, den, ctx_acc);
    k_score_ctx<<<Bsz * NLB, 512, 0, stream>>>(feat, w1tf, hp_part, W1b, W2b,
                                               Vk, Vb, el_arr, den, ctx_acc);
    k_finalize<<<Bsz * 4, 256, 0, stream>>>(el_arr, den, ctx_acc, ctx, wout);
}